// Round 2
// baseline (5711.956 us; speedup 1.0000x reference)
//
#include <hip/hip_runtime.h>
#include <cstdint>
#include <cstddef>

#define B_   16
#define N_   2048
#define D_   128
#define F_   1024
#define H1_  512
#define OUT_ 50

static constexpr float BN_EPS = 1e-5f;

// ---------------------------------------------------------------------------
// Generic 32x32-tiled transpose: out[c*R + r] = in[r*ldIn + c], r<R, c<C.
// blockDim (32,8). grid (ceil(C/32), ceil(R/32), batches)
// ---------------------------------------------------------------------------
__global__ void transpose_k(const float* __restrict__ in, float* __restrict__ out,
                            int R, int C, int ldIn,
                            long inBatchStride, long outBatchStride) {
  __shared__ __align__(16) float tile[32][33];
  in  += (long)blockIdx.z * inBatchStride;
  out += (long)blockIdx.z * outBatchStride;
  int r0 = blockIdx.y * 32, c0 = blockIdx.x * 32;
  int tx = threadIdx.x, ty = threadIdx.y;
  #pragma unroll
  for (int i = 0; i < 32; i += 8) {
    int r = r0 + ty + i, c = c0 + tx;
    tile[ty + i][tx] = (r < R && c < C) ? in[(long)r * ldIn + c] : 0.f;
  }
  __syncthreads();
  #pragma unroll
  for (int i = 0; i < 32; i += 8) {
    int c = c0 + ty + i, r = r0 + tx;
    if (c < C && r < R) out[(long)c * R + r] = tile[tx][ty + i];
  }
}

// ---------------------------------------------------------------------------
// conv1 (K=3) + bn1 + relu.  grid (N/256, 128, g), block 256.  x pre-offset.
// ---------------------------------------------------------------------------
__global__ void conv1_bn_relu(const float* __restrict__ x, const float* __restrict__ w1,
                              const float* __restrict__ g, const float* __restrict__ bb,
                              const float* __restrict__ m, const float* __restrict__ v,
                              float* __restrict__ h0) {
  int n = blockIdx.x * 256 + threadIdx.x;
  int o = blockIdx.y;
  int b = blockIdx.z;
  const float* xb = x + (long)b * 3 * N_;
  float val = w1[o * 3 + 0] * xb[n] + w1[o * 3 + 1] * xb[N_ + n] + w1[o * 3 + 2] * xb[2 * N_ + n];
  float sc = g[o] * rsqrtf(v[o] + BN_EPS);
  float sh = bb[o] - m[o] * sc;
  val = val * sc + sh;
  h0[((long)b * D_ + o) * N_ + n] = fmaxf(val, 0.f);
}

// ---------------------------------------------------------------------------
// Tiled channel-GEMM: out[b][o][n] = epi( sum_k WT[k*ldWT+o] * (X - Xsub)[b][k][n] )
// All batch pointers are pre-offset by the launcher; blockIdx.z = local batch.
// mode: 0 = raw, 1 = relu, 2 = leaky(0.2).  bn applied iff bng!=null.
// residual added (after act) iff res!=null.
// grid (N/64, ceil(Ofull/64), g), block 256
// ---------------------------------------------------------------------------
__global__ __launch_bounds__(256)
void gemm_cn(const float* __restrict__ WT, int ldWT,
             const float* __restrict__ X, long strideXb,
             const float* __restrict__ Xsub, long strideXsubB,
             const float* __restrict__ bias,
             const float* __restrict__ perBO, int perBOld,
             const float* __restrict__ bng, const float* __restrict__ bnb,
             const float* __restrict__ bnm, const float* __restrict__ bnv,
             const float* __restrict__ res, long strideResB,
             float* __restrict__ out, long strideOutB,
             int K, int Ofull, int mode) {
  __shared__ __align__(16) float Wt[32][68];
  __shared__ __align__(16) float Xt[32][68];
  int tid = threadIdx.x;
  int tx = tid & 15, ty = tid >> 4;
  int n0 = blockIdx.x * 64;
  int o0 = blockIdx.y * 64;
  int b  = blockIdx.z;
  const float* Xb  = X + (long)b * strideXb;
  const float* Xsb = Xsub ? Xsub + (long)b * strideXsubB : nullptr;
  float acc[4][4] = {};
  for (int kc = 0; kc < K; kc += 32) {
    {
      int oo = tid & 63, k0 = tid >> 6;
      #pragma unroll
      for (int it = 0; it < 8; ++it) {
        int k = k0 + it * 4;
        int o = o0 + oo;
        Wt[k][oo] = (o < Ofull) ? WT[(long)(kc + k) * ldWT + o] : 0.f;
      }
    }
    {
      int nn = tid & 63, k0 = tid >> 6;
      #pragma unroll
      for (int it = 0; it < 8; ++it) {
        int k = k0 + it * 4;
        long idx = (long)(kc + k) * N_ + n0 + nn;
        float xval = Xb[idx];
        if (Xsb) xval -= Xsb[idx];
        Xt[k][nn] = xval;
      }
    }
    __syncthreads();
    #pragma unroll
    for (int k = 0; k < 32; ++k) {
      float4 a  = *(const float4*)&Wt[k][ty * 4];
      float4 bq = *(const float4*)&Xt[k][tx * 4];
      float av[4] = {a.x, a.y, a.z, a.w};
      float bv[4] = {bq.x, bq.y, bq.z, bq.w};
      #pragma unroll
      for (int i = 0; i < 4; ++i)
        #pragma unroll
        for (int j = 0; j < 4; ++j)
          acc[i][j] += av[i] * bv[j];
    }
    __syncthreads();
  }
  #pragma unroll
  for (int i = 0; i < 4; ++i) {
    int o = o0 + ty * 4 + i;
    if (o >= Ofull) continue;
    float bi = bias ? bias[o] : 0.f;
    if (perBO) bi += perBO[(long)b * perBOld + o];
    float sc = 1.f, sh = 0.f;
    if (bng) { sc = bng[o] * rsqrtf(bnv[o] + BN_EPS); sh = bnb[o] - bnm[o] * sc; }
    long rowBase = (long)b * strideOutB + (long)o * N_ + n0 + tx * 4;
    const float* resRow = res ? res + (long)b * strideResB + (long)o * N_ + n0 + tx * 4 : nullptr;
    float tmp[4];
    #pragma unroll
    for (int j = 0; j < 4; ++j) {
      float val = acc[i][j] + bi;
      val = val * sc + sh;
      if (mode == 1)      val = fmaxf(val, 0.f);
      else if (mode == 2) val = (val >= 0.f) ? val : 0.2f * val;
      if (resRow) val += resRow[j];
      tmp[j] = val;
    }
    *(float4*)&out[rowBase] = *(const float4*)tmp;
  }
}

// ---------------------------------------------------------------------------
// energy: P[bL][n][m] = sum_d xk[bL][d][n] * xk[bL][d][m]   (Gram, K=128)
// xk pre-offset to subgroup start.  grid (N/64, N/64, Gp), block 256
// ---------------------------------------------------------------------------
__global__ __launch_bounds__(256)
void energy_k(const float* __restrict__ xk, float* __restrict__ P) {
  __shared__ __align__(16) float An[32][68];
  __shared__ __align__(16) float Am[32][68];
  int tid = threadIdx.x, tx = tid & 15, ty = tid >> 4;
  int m0 = blockIdx.x * 64, n0 = blockIdx.y * 64;
  int bL = blockIdx.z;
  const float* A = xk + (long)bL * D_ * N_;
  float acc[4][4] = {};
  for (int kc = 0; kc < D_; kc += 32) {
    int c = tid & 63, k0 = tid >> 6;
    #pragma unroll
    for (int it = 0; it < 8; ++it) {
      int k = k0 + it * 4;
      An[k][c] = A[(long)(kc + k) * N_ + n0 + c];
      Am[k][c] = A[(long)(kc + k) * N_ + m0 + c];
    }
    __syncthreads();
    #pragma unroll
    for (int k = 0; k < 32; ++k) {
      float4 a  = *(const float4*)&An[k][ty * 4];
      float4 bq = *(const float4*)&Am[k][tx * 4];
      float av[4] = {a.x, a.y, a.z, a.w};
      float bv[4] = {bq.x, bq.y, bq.z, bq.w};
      #pragma unroll
      for (int i = 0; i < 4; ++i)
        #pragma unroll
        for (int j = 0; j < 4; ++j)
          acc[i][j] += av[i] * bv[j];
    }
    __syncthreads();
  }
  #pragma unroll
  for (int i = 0; i < 4; ++i) {
    int n = n0 + ty * 4 + i;
    *(float4*)&P[((long)bL * N_ + n) * N_ + m0 + tx * 4] = *(const float4*)acc[i];
  }
}

// ---------------------------------------------------------------------------
// row softmax (in place). grid (N, Gp), block 256; 8 elems/thread
// ---------------------------------------------------------------------------
__global__ __launch_bounds__(256)
void softmax_k(float* __restrict__ P) {
  long rowOff = ((long)blockIdx.y * N_ + blockIdx.x) * N_;
  float4* r = (float4*)(P + rowOff);
  int tid = threadIdx.x;
  float4 a = r[tid];
  float4 c = r[tid + 256];
  float mx = fmaxf(fmaxf(fmaxf(a.x, a.y), fmaxf(a.z, a.w)),
                   fmaxf(fmaxf(c.x, c.y), fmaxf(c.z, c.w)));
  #pragma unroll
  for (int off = 32; off; off >>= 1) mx = fmaxf(mx, __shfl_xor(mx, off));
  __shared__ float rm[4];
  __shared__ float rs[4];
  int wid = tid >> 6, lane = tid & 63;
  if (lane == 0) rm[wid] = mx;
  __syncthreads();
  mx = fmaxf(fmaxf(rm[0], rm[1]), fmaxf(rm[2], rm[3]));
  a.x = __expf(a.x - mx); a.y = __expf(a.y - mx); a.z = __expf(a.z - mx); a.w = __expf(a.w - mx);
  c.x = __expf(c.x - mx); c.y = __expf(c.y - mx); c.z = __expf(c.z - mx); c.w = __expf(c.w - mx);
  float s = a.x + a.y + a.z + a.w + c.x + c.y + c.z + c.w;
  #pragma unroll
  for (int off = 32; off; off >>= 1) s += __shfl_xor(s, off);
  if (lane == 0) rs[wid] = s;
  __syncthreads();
  s = rs[0] + rs[1] + rs[2] + rs[3];
  float inv = 1.f / s;
  a.x *= inv; a.y *= inv; a.z *= inv; a.w *= inv;
  c.x *= inv; c.y *= inv; c.z *= inv; c.w *= inv;
  r[tid] = a;
  r[tid + 256] = c;
}

// ---------------------------------------------------------------------------
// column sums of P (local subgroup indexing). grid (N/256, Gp), block 256
// ---------------------------------------------------------------------------
__global__ void colsum_k(const float* __restrict__ P, float* __restrict__ colsum) {
  int m = blockIdx.x * 256 + threadIdx.x;
  int bL = blockIdx.y;
  const float* base = P + (long)bL * N_ * N_ + m;
  float s = 0.f;
  #pragma unroll 4
  for (int n = 0; n < N_; ++n) s += base[(long)n * N_];
  colsum[(long)bL * N_ + m] = s;
}

// ---------------------------------------------------------------------------
// x_r[bL][d][m] = (sum_n xvT[bL][n][d] * P[bL][n][m]) / (1e-9 + colsum[bL][m])
// xvT/xr pre-offset to subgroup start.  grid (N/64, D/64, Gp), block 256
// ---------------------------------------------------------------------------
__global__ __launch_bounds__(256)
void attnv_k(const float* __restrict__ xvT, const float* __restrict__ P,
             const float* __restrict__ colsum, float* __restrict__ xr) {
  __shared__ __align__(16) float At[32][68];
  __shared__ __align__(16) float Bt[32][68];
  int tid = threadIdx.x, tx = tid & 15, ty = tid >> 4;
  int m0 = blockIdx.x * 64, d0 = blockIdx.y * 64;
  int bL = blockIdx.z;
  const float* A  = xvT + (long)bL * N_ * D_;
  const float* Pb = P + (long)bL * N_ * N_;
  float acc[4][4] = {};
  for (int nc = 0; nc < N_; nc += 32) {
    int c = tid & 63, k0 = tid >> 6;
    #pragma unroll
    for (int it = 0; it < 8; ++it) {
      int k = k0 + it * 4;
      At[k][c] = A[(long)(nc + k) * D_ + d0 + c];
      Bt[k][c] = Pb[(long)(nc + k) * N_ + m0 + c];
    }
    __syncthreads();
    #pragma unroll
    for (int k = 0; k < 32; ++k) {
      float4 a  = *(const float4*)&At[k][ty * 4];
      float4 bq = *(const float4*)&Bt[k][tx * 4];
      float av[4] = {a.x, a.y, a.z, a.w};
      float bv[4] = {bq.x, bq.y, bq.z, bq.w};
      #pragma unroll
      for (int i = 0; i < 4; ++i)
        #pragma unroll
        for (int j = 0; j < 4; ++j)
          acc[i][j] += av[i] * bv[j];
    }
    __syncthreads();
  }
  float invc[4];
  #pragma unroll
  for (int j = 0; j < 4; ++j)
    invc[j] = 1.f / (1e-9f + colsum[(long)bL * N_ + m0 + tx * 4 + j]);
  #pragma unroll
  for (int i = 0; i < 4; ++i) {
    int d = d0 + ty * 4 + i;
    float tmp[4];
    #pragma unroll
    for (int j = 0; j < 4; ++j) tmp[j] = acc[i][j] * invc[j];
    *(float4*)&xr[((long)bL * D_ + d) * N_ + m0 + tx * 4] = *(const float4*)tmp;
  }
}

// ---------------------------------------------------------------------------
// pooling: max & mean over N for each (b,f), local indexing. grid (F, g), block 256
// ---------------------------------------------------------------------------
__global__ __launch_bounds__(256)
void pool_k(const float* __restrict__ fused, float* __restrict__ xmax, float* __restrict__ xavg) {
  int f = blockIdx.x, b = blockIdx.y, tid = threadIdx.x;
  const float4* r = (const float4*)(fused + ((long)b * F_ + f) * N_);
  float4 a = r[tid], c = r[tid + 256];
  float mx = fmaxf(fmaxf(fmaxf(a.x, a.y), fmaxf(a.z, a.w)),
                   fmaxf(fmaxf(c.x, c.y), fmaxf(c.z, c.w)));
  float s = a.x + a.y + a.z + a.w + c.x + c.y + c.z + c.w;
  #pragma unroll
  for (int off = 32; off; off >>= 1) { mx = fmaxf(mx, __shfl_xor(mx, off)); s += __shfl_xor(s, off); }
  __shared__ float rm[4];
  __shared__ float rs[4];
  if ((tid & 63) == 0) { rm[tid >> 6] = mx; rs[tid >> 6] = s; }
  __syncthreads();
  if (tid == 0) {
    mx = fmaxf(fmaxf(rm[0], rm[1]), fmaxf(rm[2], rm[3]));
    s = rs[0] + rs[1] + rs[2] + rs[3];
    xmax[(long)b * F_ + f] = mx;
    xavg[(long)b * F_ + f] = s * (1.f / N_);
  }
}

// ---------------------------------------------------------------------------
// pool term: pt[b][o] = sum_c ws1[o][1024+c]*xmax[b][c] + ws1[o][2048+c]*xavg[b][c]
// local indexing.  grid (H1, g), block 256
// ---------------------------------------------------------------------------
__global__ __launch_bounds__(256)
void poolterm_k(const float* __restrict__ ws1, const float* __restrict__ xmax,
                const float* __restrict__ xavg, float* __restrict__ pt) {
  int o = blockIdx.x, b = blockIdx.y, tid = threadIdx.x;
  const float* w = ws1 + (long)o * 3072;
  float s = 0.f;
  #pragma unroll
  for (int it = 0; it < 4; ++it) {
    int c = tid + it * 256;
    s += w[1024 + c] * xmax[(long)b * F_ + c] + w[2048 + c] * xavg[(long)b * F_ + c];
  }
  #pragma unroll
  for (int off = 32; off; off >>= 1) s += __shfl_xor(s, off);
  __shared__ float rs[4];
  if ((tid & 63) == 0) rs[tid >> 6] = s;
  __syncthreads();
  if (tid == 0) pt[(long)b * H1_ + o] = rs[0] + rs[1] + rs[2] + rs[3];
}

// ---------------------------------------------------------------------------
extern "C" void kernel_launch(void* const* d_in, const int* in_sizes, int n_in,
                              void* d_out, int out_size, void* d_ws, size_t ws_size,
                              hipStream_t stream) {
  const float* x      = (const float*)d_in[0];
  const float* w1     = (const float*)d_in[1];
  const float* w2     = (const float*)d_in[2];
  const float* bn1_g  = (const float*)d_in[3];
  const float* bn1_b  = (const float*)d_in[4];
  const float* bn1_m  = (const float*)d_in[5];
  const float* bn1_v  = (const float*)d_in[6];
  const float* bn2_g  = (const float*)d_in[7];
  const float* bn2_b  = (const float*)d_in[8];
  const float* bn2_m  = (const float*)d_in[9];
  const float* bn2_v  = (const float*)d_in[10];
  const float* sa_wqk = (const float*)d_in[11];
  const float* sa_wv  = (const float*)d_in[12];
  const float* sa_bv  = (const float*)d_in[13];
  const float* sa_wt  = (const float*)d_in[14];
  const float* sa_bt  = (const float*)d_in[15];
  const float* sa_g   = (const float*)d_in[16];
  const float* sa_b   = (const float*)d_in[17];
  const float* sa_m   = (const float*)d_in[18];
  const float* sa_v   = (const float*)d_in[19];
  const float* wf     = (const float*)d_in[20];
  const float* bnf_g  = (const float*)d_in[21];
  const float* bnf_b  = (const float*)d_in[22];
  const float* bnf_m  = (const float*)d_in[23];
  const float* bnf_v  = (const float*)d_in[24];
  const float* ws1    = (const float*)d_in[25];
  const float* bs1    = (const float*)d_in[26];
  const float* bns1_g = (const float*)d_in[27];
  const float* bns1_b = (const float*)d_in[28];
  const float* bns1_m = (const float*)d_in[29];
  const float* bns1_v = (const float*)d_in[30];
  const float* ws2    = (const float*)d_in[31];
  const float* bs2    = (const float*)d_in[32];
  const float* bns2_g = (const float*)d_in[33];
  const float* bns2_b = (const float*)d_in[34];
  const float* bns2_m = (const float*)d_in[35];
  const float* bns2_v = (const float*)d_in[36];
  float* out = (float*)d_out;

  float* ws = (float*)d_ws;
  size_t off = 0;
  auto alloc = [&](size_t n) { float* p = ws + off; off += (n + 63) & ~(size_t)63; return p; };

  // ---- fixed small allocations (weights transposed + reductions) ----
  float* w2T   = alloc(128 * 128);
  float* wqkT  = alloc(4 * 128 * 128);
  float* wvT   = alloc(4 * 128 * 128);
  float* wtT   = alloc(4 * 128 * 128);
  float* wfT   = alloc((size_t)512 * F_);
  float* ws1T  = alloc((size_t)F_ * H1_);
  float* ws2T  = alloc((size_t)512 * OUT_);
  float* cs    = alloc((size_t)16 * N_);
  float* xmaxB = alloc((size_t)16 * F_);
  float* xavgB = alloc((size_t)16 * F_);
  float* ptB   = alloc((size_t)16 * H1_);
  size_t fixedOff = off;

  // ---- choose batch group Gb and attention subgroup Gp from ws_size ----
  size_t wsFloats = ws_size / 4;
  const int GbC[] = {16, 16, 16, 8, 8, 8, 4, 4, 4, 2, 2, 1};
  const int GpC[] = {16,  8,  4, 8, 4, 2, 4, 2, 1, 2, 1, 1};
  int Gb = 1, Gp = 1;
  for (int c = 0; c < 12; ++c) {
    size_t grp = (size_t)GbC[c] * (262144 /*h1*/ + 4 * 262144 /*xk..xr*/ + 1048576 /*feats*/);
    size_t bigP = (size_t)GpC[c] * 4194304;           // P
    size_t bigF = (size_t)GbC[c] * 2097152;           // fused
    size_t big  = bigP > bigF ? bigP : bigF;
    if (fixedOff + grp + big + 1024 <= wsFloats) { Gb = GbC[c]; Gp = GpC[c]; break; }
  }

  // ---- group-sized buffers (aliased) ----
  float* h1    = alloc((size_t)Gb * 262144);
  float* attnB = alloc((size_t)Gb * 4 * 262144);  // xk | xv | xvT | xr  (hs1 aliases all)
  float* xk  = attnB;
  float* xv  = attnB + (size_t)Gb * 262144;
  float* xvT = attnB + (size_t)Gb * 2 * 262144;
  float* xr  = attnB + (size_t)Gb * 3 * 262144;
  float* h0  = xk;                                 // phase-1 alias
  float* hs1 = attnB;                              // phase-3 alias (Gb*H1*N = Gb*2^20)
  float* feats = alloc((size_t)Gb * 1048576);
  float* big   = ws + off;                         // P (attention) / fused (phase 3)
  float* P     = big;
  float* fused = big;

  dim3 tb(32, 8);
  // ---- one-time weight transposes (K-major for gemm_cn) ----
  transpose_k<<<dim3(4, 4, 1),   tb, 0, stream>>>(w2,  w2T,  128, 128, 128, 0, 0);
  transpose_k<<<dim3(4, 4, 4),   tb, 0, stream>>>(sa_wqk, wqkT, 128, 128, 128, 128 * 128, 128 * 128);
  transpose_k<<<dim3(4, 4, 4),   tb, 0, stream>>>(sa_wv,  wvT,  128, 128, 128, 128 * 128, 128 * 128);
  transpose_k<<<dim3(4, 4, 4),   tb, 0, stream>>>(sa_wt,  wtT,  128, 128, 128, 128 * 128, 128 * 128);
  transpose_k<<<dim3(16, 32, 1), tb, 0, stream>>>(wf,  wfT,  F_, 512, 512, 0, 0);
  transpose_k<<<dim3(32, 16, 1), tb, 0, stream>>>(ws1, ws1T, H1_, 1024, 3072, 0, 0);  // first 1024 cols
  transpose_k<<<dim3(16, 2, 1),  tb, 0, stream>>>(ws2, ws2T, OUT_, 512, 512, 0, 0);

  for (int b0 = 0; b0 < B_; b0 += Gb) {
    int g = Gb;  // Gb divides 16
    // conv1 + bn1 + relu -> h0
    conv1_bn_relu<<<dim3(N_ / 256, 128, g), 256, 0, stream>>>(
        x + (long)b0 * 3 * N_, w1, bn1_g, bn1_b, bn1_m, bn1_v, h0);
    // conv2 + bn2 + relu -> h1
    gemm_cn<<<dim3(32, 2, g), 256, 0, stream>>>(
        w2T, 128, h0, (long)D_ * N_, nullptr, 0, nullptr, nullptr, 0,
        bn2_g, bn2_b, bn2_m, bn2_v, nullptr, 0, h1, (long)D_ * N_, 128, 128, 1);

    for (int i = 0; i < 4; ++i) {
      const float* li = (i == 0) ? h1 : feats + (size_t)(i - 1) * 128 * N_;
      long liStride = (i == 0) ? (long)D_ * N_ : (long)512 * N_;
      gemm_cn<<<dim3(32, 2, g), 256, 0, stream>>>(
          wqkT + (size_t)i * 128 * 128, 128, li, liStride, nullptr, 0, nullptr, nullptr, 0,
          nullptr, nullptr, nullptr, nullptr, nullptr, 0, xk, (long)D_ * N_, 128, 128, 0);
      gemm_cn<<<dim3(32, 2, g), 256, 0, stream>>>(
          wvT + (size_t)i * 128 * 128, 128, li, liStride, nullptr, 0, sa_bv + i * 128, nullptr, 0,
          nullptr, nullptr, nullptr, nullptr, nullptr, 0, xv, (long)D_ * N_, 128, 128, 0);
      transpose_k<<<dim3(64, 4, g), tb, 0, stream>>>(xv, xvT, D_, N_, N_,
                                                     (long)D_ * N_, (long)D_ * N_);
      for (int s0 = 0; s0 < g; s0 += Gp) {
        int gs = (Gp < g - s0) ? Gp : (g - s0);
        energy_k<<<dim3(32, 32, gs), 256, 0, stream>>>(xk + (size_t)s0 * D_ * N_, P);
        softmax_k<<<dim3(N_, gs), 256, 0, stream>>>(P);
        colsum_k<<<dim3(N_ / 256, gs), 256, 0, stream>>>(P, cs);
        attnv_k<<<dim3(32, 2, gs), 256, 0, stream>>>(xvT + (size_t)s0 * N_ * D_, P, cs,
                                                     xr + (size_t)s0 * D_ * N_);
      }
      // feats_i = li + relu(bn(wt @ (li - xr) + bt))
      gemm_cn<<<dim3(32, 2, g), 256, 0, stream>>>(
          wtT + (size_t)i * 128 * 128, 128, li, liStride, xr, (long)D_ * N_,
          sa_bt + i * 128, nullptr, 0,
          sa_g + i * 128, sa_b + i * 128, sa_m + i * 128, sa_v + i * 128,
          li, liStride, feats + (size_t)i * 128 * N_, (long)512 * N_, 128, 128, 1);
    }

    // fused = leakyrelu(bn(wf @ feats))
    gemm_cn<<<dim3(32, 16, g), 256, 0, stream>>>(
        wfT, F_, feats, (long)512 * N_, nullptr, 0, nullptr, nullptr, 0,
        bnf_g, bnf_b, bnf_m, bnf_v, nullptr, 0, fused, (long)F_ * N_, 512, F_, 2);
    pool_k<<<dim3(F_, g), 256, 0, stream>>>(fused, xmaxB, xavgB);
    poolterm_k<<<dim3(H1_, g), 256, 0, stream>>>(ws1, xmaxB, xavgB, ptB);
    // hs1 = relu(bn(ws1 @ [fused;gmax;gavg] + bs1))  (pool part folded into perBO)
    gemm_cn<<<dim3(32, 8, g), 256, 0, stream>>>(
        ws1T, H1_, fused, (long)F_ * N_, nullptr, 0, bs1, ptB, H1_,
        bns1_g, bns1_b, bns1_m, bns1_v, nullptr, 0, hs1, (long)H1_ * N_, 1024, H1_, 1);
    // out = relu(bn(ws2 @ hs1 + bs2))
    gemm_cn<<<dim3(32, 1, g), 256, 0, stream>>>(
        ws2T, OUT_, hs1, (long)H1_ * N_, nullptr, 0, bs2, nullptr, 0,
        bns2_g, bns2_b, bns2_m, bns2_v, nullptr, 0, out + (long)b0 * OUT_ * N_,
        (long)OUT_ * N_, 512, OUT_, 1);
  }
}

// Round 3
// 1372.761 us; speedup vs baseline: 4.1609x; 4.1609x over previous
//
#include <hip/hip_runtime.h>
#include <cstdint>
#include <cstddef>

#define B_   16
#define N_   2048
#define D_   128
#define F_   1024
#define H1_  512
#define OUT_ 50

static constexpr float BN_EPS = 1e-5f;

typedef __attribute__((ext_vector_type(8))) short short8;
typedef __attribute__((ext_vector_type(4))) float f32x4;

__device__ inline unsigned short f2bf(float f) {
  union { float f; unsigned u; } v; v.f = f;
  unsigned r = v.u + 0x7fff + ((v.u >> 16) & 1);
  return (unsigned short)(r >> 16);
}

// ---------------------------------------------------------------------------
// cast fp32 [R][ldSrc] (first C cols) -> bf16 [R][C] row-major
// ---------------------------------------------------------------------------
__global__ void cast2d_k(const float* __restrict__ src, unsigned short* __restrict__ dst,
                         int R, int C, int ldSrc) {
  long i = (long)blockIdx.x * 256 + threadIdx.x;
  if (i >= (long)R * C) return;
  int r = (int)(i / C), c = (int)(i % C);
  dst[i] = f2bf(src[(long)r * ldSrc + c]);
}

// ---------------------------------------------------------------------------
// conv1 (3->128) + bn + relu, token-major fp32 out. grid (N, g), block 128
// ---------------------------------------------------------------------------
__global__ void conv1_k(const float* __restrict__ x, const float* __restrict__ w1,
                        const float* __restrict__ g, const float* __restrict__ bb,
                        const float* __restrict__ m, const float* __restrict__ v,
                        float* __restrict__ h0) {
  int o = threadIdx.x, n = blockIdx.x, b = blockIdx.y;
  const float* xb = x + (long)b * 3 * N_;
  float val = w1[o * 3 + 0] * xb[n] + w1[o * 3 + 1] * xb[N_ + n] + w1[o * 3 + 2] * xb[2 * N_ + n];
  float sc = g[o] * rsqrtf(v[o] + BN_EPS);
  val = val * sc + (bb[o] - m[o] * sc);
  h0[((long)b * N_ + n) * D_ + o] = fmaxf(val, 0.f);
}

// ---------------------------------------------------------------------------
// Token-major MFMA GEMM: out[n][o] = epi( sum_k (X1-X2)[n][k] * W[o][k] )
// X1/X2 fp32 token-major (ld = row stride), W bf16 [O][K] row-major.
// Tile 128n x 128o, block 256 (4 waves 2x2), BK=32, 16x16x32 bf16 MFMA.
// outFmode/outHmode: 0 none, 1 token [n][o], 2 channel [o][n].
// act: 0 none, 1 relu, 2 leaky(0.2). res (fp32 token) added after act.
// ---------------------------------------------------------------------------
__global__ __launch_bounds__(256)
void gemm_tok(const unsigned short* __restrict__ Wb,
              const float* __restrict__ X1, long sX1, int ldX1,
              const float* __restrict__ X2, long sX2, int ldX2,
              const float* __restrict__ bias,
              const float* __restrict__ perBO, int ldPBO,
              const float* __restrict__ bng, const float* __restrict__ bnb,
              const float* __restrict__ bnm, const float* __restrict__ bnv,
              const float* __restrict__ res, long sRes, int ldRes,
              float* __restrict__ outF, long sOutF, int ldOutF, int outFmode,
              unsigned short* __restrict__ outH, long sOutH, int ldOutH, int outHmode,
              int K, int O, int act) {
  __shared__ unsigned short lA[128 * 40];  // [n][32+8] bf16, 80B rows
  __shared__ unsigned short lB[128 * 40];
  int tid = threadIdx.x;
  int n0 = blockIdx.x * 128, o0 = blockIdx.y * 128, b = blockIdx.z;
  int wave = tid >> 6, lane = tid & 63;
  int wr = wave >> 1, wc = wave & 1;
  int quad = lane >> 4, l15 = lane & 15;
  const float* Xb1 = X1 + (long)b * sX1;
  const float* Xb2 = X2 ? X2 + (long)b * sX2 : nullptr;

  f32x4 acc[4][4];
  #pragma unroll
  for (int i = 0; i < 4; ++i)
    #pragma unroll
    for (int j = 0; j < 4; ++j) acc[i][j] = (f32x4){0.f, 0.f, 0.f, 0.f};

  int row = tid >> 1, kh = (tid & 1) * 16;
  for (int kc = 0; kc < K; kc += 32) {
    // stage A (fp32 -> bf16)
    {
      const float* src = Xb1 + (long)(n0 + row) * ldX1 + kc + kh;
      float a[16];
      #pragma unroll
      for (int q = 0; q < 4; ++q) *(float4*)&a[q * 4] = *(const float4*)(src + q * 4);
      if (Xb2) {
        const float* s2 = Xb2 + (long)(n0 + row) * ldX2 + kc + kh;
        #pragma unroll
        for (int q = 0; q < 4; ++q) {
          float4 t = *(const float4*)(s2 + q * 4);
          a[q * 4 + 0] -= t.x; a[q * 4 + 1] -= t.y; a[q * 4 + 2] -= t.z; a[q * 4 + 3] -= t.w;
        }
      }
      unsigned short t[16];
      #pragma unroll
      for (int q = 0; q < 16; ++q) t[q] = f2bf(a[q]);
      *(uint4*)&lA[row * 40 + kh] = *(uint4*)&t[0];
      *(uint4*)&lA[row * 40 + kh + 8] = *(uint4*)&t[8];
    }
    // stage B (bf16 copy, guard o < O)
    {
      int o = o0 + row;
      if (o < O) {
        const unsigned short* src = Wb + (long)o * K + kc + kh;
        *(uint4*)&lB[row * 40 + kh] = *(const uint4*)(src);
        *(uint4*)&lB[row * 40 + kh + 8] = *(const uint4*)(src + 8);
      } else {
        uint4 z = {0, 0, 0, 0};
        *(uint4*)&lB[row * 40 + kh] = z;
        *(uint4*)&lB[row * 40 + kh + 8] = z;
      }
    }
    __syncthreads();
    short8 af[4], bf[4];
    #pragma unroll
    for (int mt = 0; mt < 4; ++mt) af[mt] = *(const short8*)&lA[(wr * 64 + mt * 16 + l15) * 40 + quad * 8];
    #pragma unroll
    for (int ot = 0; ot < 4; ++ot) bf[ot] = *(const short8*)&lB[(wc * 64 + ot * 16 + l15) * 40 + quad * 8];
    #pragma unroll
    for (int mt = 0; mt < 4; ++mt)
      #pragma unroll
      for (int ot = 0; ot < 4; ++ot)
        acc[mt][ot] = __builtin_amdgcn_mfma_f32_16x16x32_bf16(af[mt], bf[ot], acc[mt][ot], 0, 0, 0);
    __syncthreads();
  }

  // epilogue
  #pragma unroll
  for (int ot = 0; ot < 4; ++ot) {
    int o = o0 + wc * 64 + ot * 16 + l15;
    if (o >= O) continue;
    float bi = bias ? bias[o] : 0.f;
    if (perBO) bi += perBO[(long)b * ldPBO + o];
    float sc = 1.f, sh = 0.f;
    if (bng) { sc = bng[o] * rsqrtf(bnv[o] + BN_EPS); sh = bnb[o] - bnm[o] * sc; }
    #pragma unroll
    for (int mt = 0; mt < 4; ++mt) {
      int nb = n0 + wr * 64 + mt * 16 + quad * 4;
      float vals[4];
      #pragma unroll
      for (int r = 0; r < 4; ++r) {
        float val = acc[mt][ot][r] + bi;
        val = val * sc + sh;
        if (act == 1)      val = fmaxf(val, 0.f);
        else if (act == 2) val = (val >= 0.f) ? val : 0.2f * val;
        if (res) val += res[(long)b * sRes + (long)(nb + r) * ldRes + o];
        vals[r] = val;
      }
      if (outFmode == 1) {
        #pragma unroll
        for (int r = 0; r < 4; ++r) outF[(long)b * sOutF + (long)(nb + r) * ldOutF + o] = vals[r];
      } else if (outFmode == 2) {
        *(float4*)&outF[(long)b * sOutF + (long)o * ldOutF + nb] = *(float4*)vals;
      }
      if (outHmode == 1) {
        #pragma unroll
        for (int r = 0; r < 4; ++r) outH[(long)b * sOutH + (long)(nb + r) * ldOutH + o] = f2bf(vals[r]);
      } else if (outHmode == 2) {
        unsigned short t[4];
        #pragma unroll
        for (int r = 0; r < 4; ++r) t[r] = f2bf(vals[r]);
        *(uint2*)&outH[(long)b * sOutH + (long)o * ldOutH + nb] = *(uint2*)&t[0];
      }
    }
  }
}

// ---------------------------------------------------------------------------
// Gram row-stats. E[n][m] = xk[n]·xk[m] (symmetric). 16x16x32 MFMA.
// mode 0: rowmax mx[n], rowsum rs[n] of exp (online).
// mode 1: colsum cs[n] = sum_m exp(E[n][m]-mx[m])/rs[m]   (by symmetry).
// xk bf16 token-major [2048][128]. grid (32, g), block 256 (wave = 16 rows).
// ---------------------------------------------------------------------------
__global__ __launch_bounds__(256)
void gram_stats(const unsigned short* __restrict__ xk, long sXk,
                float* __restrict__ mx, float* __restrict__ rs,
                float* __restrict__ cs, int mode) {
  __shared__ unsigned short lK[64 * 136];  // [m][128+8]
  __shared__ float lmx[2048], lrs[2048];
  int tid = threadIdx.x, wave = tid >> 6, lane = tid & 63;
  int quad = lane >> 4, l15 = lane & 15;
  int n0 = blockIdx.x * 64, b = blockIdx.y;
  const unsigned short* Kp = xk + (long)b * sXk;
  if (mode == 1) {
    for (int i = tid; i < 2048; i += 256) { lmx[i] = mx[(long)b * 2048 + i]; lrs[i] = rs[(long)b * 2048 + i]; }
  }
  short8 afr[4];
  {
    const unsigned short* arow = Kp + (long)(n0 + wave * 16 + l15) * 128;
    #pragma unroll
    for (int kf = 0; kf < 4; ++kf) afr[kf] = *(const short8*)(arow + kf * 32 + quad * 8);
  }
  float runm[4], runs[4];
  #pragma unroll
  for (int r = 0; r < 4; ++r) { runm[r] = -1e30f; runs[r] = 0.f; }

  for (int m0 = 0; m0 < 2048; m0 += 64) {
    __syncthreads();
    {
      int r = tid >> 2, seg = tid & 3;
      const unsigned short* src = Kp + (long)(m0 + r) * 128 + seg * 32;
      #pragma unroll
      for (int q = 0; q < 4; ++q)
        *(uint4*)&lK[r * 136 + seg * 32 + q * 8] = *(const uint4*)(src + q * 8);
    }
    __syncthreads();
    #pragma unroll
    for (int mf = 0; mf < 4; ++mf) {
      f32x4 s = (f32x4){0.f, 0.f, 0.f, 0.f};
      #pragma unroll
      for (int kf = 0; kf < 4; ++kf) {
        short8 bfr = *(const short8*)&lK[(mf * 16 + l15) * 136 + kf * 32 + quad * 8];
        s = __builtin_amdgcn_mfma_f32_16x16x32_bf16(afr[kf], bfr, s, 0, 0, 0);
      }
      int col = m0 + mf * 16 + l15;
      if (mode == 0) {
        #pragma unroll
        for (int r = 0; r < 4; ++r) {
          float e = s[r];
          float mn = fmaxf(runm[r], e);
          runs[r] = runs[r] * __expf(runm[r] - mn) + __expf(e - mn);
          runm[r] = mn;
        }
      } else {
        float mc = lmx[col], rcInv = 1.f / lrs[col];
        #pragma unroll
        for (int r = 0; r < 4; ++r) runs[r] += __expf(s[r] - mc) * rcInv;
      }
    }
  }
  if (mode == 0) {
    #pragma unroll
    for (int r = 0; r < 4; ++r) {
      float m = runm[r], s = runs[r];
      #pragma unroll
      for (int off = 1; off < 16; off <<= 1) {
        float mo = __shfl_xor(m, off), so = __shfl_xor(s, off);
        float mn = fmaxf(m, mo);
        s = s * __expf(m - mn) + so * __expf(mo - mn);
        m = mn;
      }
      if (l15 == 0) {
        int n = n0 + wave * 16 + quad * 4 + r;
        mx[(long)b * 2048 + n] = m; rs[(long)b * 2048 + n] = s;
      }
    }
  } else {
    #pragma unroll
    for (int r = 0; r < 4; ++r) {
      float s = runs[r];
      #pragma unroll
      for (int off = 1; off < 16; off <<= 1) s += __shfl_xor(s, off);
      if (l15 == 0) cs[(long)b * 2048 + n0 + wave * 16 + quad * 4 + r] = s;
    }
  }
}

// ---------------------------------------------------------------------------
// Fused PV: xr[m][d] = (sum_n Pn[n][m] * xv[d][n]) / (1e-9 + cs[m])
// where Pn[n][m] = exp(E[m][n]-mx[n])/rs[n]  (E symmetric; computed on the fly)
// xk bf16 token [2048][128]; xv bf16 channel [128][2048]; xr fp32 token.
// grid (32, g), block 256.
// ---------------------------------------------------------------------------
__global__ __launch_bounds__(256)
void pv_k(const unsigned short* __restrict__ xk, long sXk,
          const unsigned short* __restrict__ xv, long sXv,
          const float* __restrict__ mx, const float* __restrict__ rs,
          const float* __restrict__ cs, float* __restrict__ xr, long sXr) {
  __shared__ unsigned short lK[64 * 136];      // xk n-tile [n][128+8]
  __shared__ unsigned short lV[128 * 72];      // xv tile [d][64+8]
  __shared__ unsigned short lP[4][16 * 72];    // per-wave P tile [m][64+8]
  __shared__ float lmx[2048], lrs[2048];
  int tid = threadIdx.x, wave = tid >> 6, lane = tid & 63;
  int quad = lane >> 4, l15 = lane & 15;
  int m0 = blockIdx.x * 64, b = blockIdx.y;
  const unsigned short* Kp = xk + (long)b * sXk;
  const unsigned short* Vp = xv + (long)b * sXv;
  for (int i = tid; i < 2048; i += 256) { lmx[i] = mx[(long)b * 2048 + i]; lrs[i] = rs[(long)b * 2048 + i]; }
  short8 akr[4];
  {
    const unsigned short* arow = Kp + (long)(m0 + wave * 16 + l15) * 128;
    #pragma unroll
    for (int kf = 0; kf < 4; ++kf) akr[kf] = *(const short8*)(arow + kf * 32 + quad * 8);
  }
  f32x4 acc[8];
  #pragma unroll
  for (int dt = 0; dt < 8; ++dt) acc[dt] = (f32x4){0.f, 0.f, 0.f, 0.f};

  for (int n0 = 0; n0 < 2048; n0 += 64) {
    __syncthreads();
    {
      int r = tid >> 2, seg = tid & 3;
      const unsigned short* src = Kp + (long)(n0 + r) * 128 + seg * 32;
      #pragma unroll
      for (int q = 0; q < 4; ++q)
        *(uint4*)&lK[r * 136 + seg * 32 + q * 8] = *(const uint4*)(src + q * 8);
    }
    {
      int d = tid >> 1, half = (tid & 1) * 32;
      const unsigned short* src = Vp + (long)d * 2048 + n0 + half;
      #pragma unroll
      for (int q = 0; q < 4; ++q)
        *(uint4*)&lV[d * 72 + half + q * 8] = *(const uint4*)(src + q * 8);
    }
    __syncthreads();
    // S = E[m-rows][n-cols], p = exp(S - mx[n])/rs[n] -> lP (A-layout)
    #pragma unroll
    for (int nf = 0; nf < 4; ++nf) {
      f32x4 s = (f32x4){0.f, 0.f, 0.f, 0.f};
      #pragma unroll
      for (int kf = 0; kf < 4; ++kf) {
        short8 bfr = *(const short8*)&lK[(nf * 16 + l15) * 136 + kf * 32 + quad * 8];
        s = __builtin_amdgcn_mfma_f32_16x16x32_bf16(akr[kf], bfr, s, 0, 0, 0);
      }
      int col = n0 + nf * 16 + l15;
      float mc = lmx[col], rcInv = 1.f / lrs[col];
      #pragma unroll
      for (int r = 0; r < 4; ++r) {
        float p = __expf(s[r] - mc) * rcInv;
        lP[wave][(quad * 4 + r) * 72 + nf * 16 + l15] = f2bf(p);
      }
    }
    __syncthreads();
    // PV: acc[m][d] += P[m][n-chunk] * V[d][n-chunk]
    #pragma unroll
    for (int kc = 0; kc < 2; ++kc) {
      short8 pa = *(const short8*)&lP[wave][l15 * 72 + kc * 32 + quad * 8];
      #pragma unroll
      for (int dt = 0; dt < 8; ++dt) {
        short8 vb = *(const short8*)&lV[(dt * 16 + l15) * 72 + kc * 32 + quad * 8];
        acc[dt] = __builtin_amdgcn_mfma_f32_16x16x32_bf16(pa, vb, acc[dt], 0, 0, 0);
      }
    }
  }
  float inv[4];
  #pragma unroll
  for (int r = 0; r < 4; ++r)
    inv[r] = 1.f / (1e-9f + cs[(long)b * 2048 + m0 + wave * 16 + quad * 4 + r]);
  #pragma unroll
  for (int dt = 0; dt < 8; ++dt) {
    int d = dt * 16 + l15;
    #pragma unroll
    for (int r = 0; r < 4; ++r)
      xr[(long)b * sXr + (long)(m0 + wave * 16 + quad * 4 + r) * 128 + d] = acc[dt][r] * inv[r];
  }
}

// ---------------------------------------------------------------------------
// pooling partials over n-chunks of 128. fused fp32 token [2048][1024].
// grid (4, 16, g) block 256 -> pmax/psum [g][16][1024]; then reduce.
// ---------------------------------------------------------------------------
__global__ void poolpart_k(const float* __restrict__ fused, long sF,
                           float* __restrict__ pmax, float* __restrict__ psum) {
  int f = blockIdx.x * 256 + threadIdx.x, b = blockIdx.z;
  const float* base = fused + (long)b * sF + (long)blockIdx.y * 128 * 1024 + f;
  float mx = -1e30f, s = 0.f;
  #pragma unroll 4
  for (int i = 0; i < 128; ++i) { float v = base[(long)i * 1024]; mx = fmaxf(mx, v); s += v; }
  pmax[((long)b * 16 + blockIdx.y) * 1024 + f] = mx;
  psum[((long)b * 16 + blockIdx.y) * 1024 + f] = s;
}

__global__ void poolred_k(const float* __restrict__ pmax, const float* __restrict__ psum,
                          float* __restrict__ xmax, float* __restrict__ xavg) {
  int f = blockIdx.x * 256 + threadIdx.x, b = blockIdx.y;
  float mx = -1e30f, s = 0.f;
  #pragma unroll
  for (int t = 0; t < 16; ++t) {
    mx = fmaxf(mx, pmax[((long)b * 16 + t) * 1024 + f]);
    s += psum[((long)b * 16 + t) * 1024 + f];
  }
  xmax[(long)b * 1024 + f] = mx;
  xavg[(long)b * 1024 + f] = s * (1.f / 2048.f);
}

// ---------------------------------------------------------------------------
// pool term (fp32, reads original ws1 cols 1024..3071). grid (512, g), block 256
// ---------------------------------------------------------------------------
__global__ __launch_bounds__(256)
void poolterm_k(const float* __restrict__ ws1, const float* __restrict__ xmax,
                const float* __restrict__ xavg, float* __restrict__ pt) {
  int o = blockIdx.x, b = blockIdx.y, tid = threadIdx.x;
  const float* w = ws1 + (long)o * 3072;
  float s = 0.f;
  #pragma unroll
  for (int it = 0; it < 4; ++it) {
    int c = tid + it * 256;
    s += w[1024 + c] * xmax[(long)b * 1024 + c] + w[2048 + c] * xavg[(long)b * 1024 + c];
  }
  #pragma unroll
  for (int off = 32; off; off >>= 1) s += __shfl_xor(s, off);
  __shared__ float rsm[4];
  if ((tid & 63) == 0) rsm[tid >> 6] = s;
  __syncthreads();
  if (tid == 0) pt[(long)b * H1_ + o] = rsm[0] + rsm[1] + rsm[2] + rsm[3];
}

// ---------------------------------------------------------------------------
extern "C" void kernel_launch(void* const* d_in, const int* in_sizes, int n_in,
                              void* d_out, int out_size, void* d_ws, size_t ws_size,
                              hipStream_t stream) {
  const float* x      = (const float*)d_in[0];
  const float* w1     = (const float*)d_in[1];
  const float* w2     = (const float*)d_in[2];
  const float* bn1_g  = (const float*)d_in[3];
  const float* bn1_b  = (const float*)d_in[4];
  const float* bn1_m  = (const float*)d_in[5];
  const float* bn1_v  = (const float*)d_in[6];
  const float* bn2_g  = (const float*)d_in[7];
  const float* bn2_b  = (const float*)d_in[8];
  const float* bn2_m  = (const float*)d_in[9];
  const float* bn2_v  = (const float*)d_in[10];
  const float* sa_wqk = (const float*)d_in[11];
  const float* sa_wv  = (const float*)d_in[12];
  const float* sa_bv  = (const float*)d_in[13];
  const float* sa_wt  = (const float*)d_in[14];
  const float* sa_bt  = (const float*)d_in[15];
  const float* sa_g   = (const float*)d_in[16];
  const float* sa_b   = (const float*)d_in[17];
  const float* sa_m   = (const float*)d_in[18];
  const float* sa_v   = (const float*)d_in[19];
  const float* wf     = (const float*)d_in[20];
  const float* bnf_g  = (const float*)d_in[21];
  const float* bnf_b  = (const float*)d_in[22];
  const float* bnf_m  = (const float*)d_in[23];
  const float* bnf_v  = (const float*)d_in[24];
  const float* ws1    = (const float*)d_in[25];
  const float* bs1    = (const float*)d_in[26];
  const float* bns1_g = (const float*)d_in[27];
  const float* bns1_b = (const float*)d_in[28];
  const float* bns1_m = (const float*)d_in[29];
  const float* bns1_v = (const float*)d_in[30];
  const float* ws2    = (const float*)d_in[31];
  const float* bs2    = (const float*)d_in[32];
  const float* bns2_g = (const float*)d_in[33];
  const float* bns2_b = (const float*)d_in[34];
  const float* bns2_m = (const float*)d_in[35];
  const float* bns2_v = (const float*)d_in[36];
  float* out = (float*)d_out;

  float* ws = (float*)d_ws;
  size_t off = 0;
  auto alloc  = [&](size_t n) { float* p = ws + off; off += (n + 63) & ~(size_t)63; return p; };
  auto allocH = [&](size_t n) { return (unsigned short*)alloc((n + 1) / 2); };

  // ---- fixed: bf16 weights + reductions ----
  unsigned short* w2b  = allocH(128 * 128);
  unsigned short* wqkb = allocH(4 * 128 * 128);
  unsigned short* wvb  = allocH(4 * 128 * 128);
  unsigned short* wtb  = allocH(4 * 128 * 128);
  unsigned short* wfb  = allocH((size_t)F_ * 512);
  unsigned short* ws1b = allocH((size_t)H1_ * 1024);
  unsigned short* ws2b = allocH((size_t)OUT_ * 512);
  float* mxB  = alloc((size_t)16 * 2048);
  float* rsB  = alloc((size_t)16 * 2048);
  float* csB  = alloc((size_t)16 * 2048);
  float* pmax = alloc((size_t)16 * 16 * 1024);
  float* psum = alloc((size_t)16 * 16 * 1024);
  float* xmaxB = alloc((size_t)16 * 1024);
  float* xavgB = alloc((size_t)16 * 1024);
  float* ptB   = alloc((size_t)16 * 512);
  size_t fixedOff = off;

  // ---- batch group size from ws_size ----
  const size_t perB = 262144 /*h0|xr*/ + 262144 /*h1*/ + 131072 /*xk bf*/ +
                      131072 /*xv bf*/ + 1048576 /*feats|hs1*/ + 2097152 /*fused*/;
  size_t wsFloats = ws_size / 4;
  int Gb = 1;
  for (int c : {16, 8, 4, 2, 1}) {
    if (fixedOff + (size_t)c * perB + 4096 <= wsFloats) { Gb = c; break; }
  }

  float* h0    = alloc((size_t)Gb * 262144);   // also xr
  float* h1    = alloc((size_t)Gb * 262144);
  unsigned short* xkb = allocH((size_t)Gb * 262144);
  unsigned short* xvb = allocH((size_t)Gb * 262144);
  float* feats = alloc((size_t)Gb * 1048576);  // also hs1
  float* fused = alloc((size_t)Gb * 2097152);
  float* xr  = h0;
  float* hs1 = feats;

  // ---- one-time weight casts ----
  cast2d_k<<<64,   256, 0, stream>>>(w2,     w2b,  128, 128, 128);
  cast2d_k<<<256,  256, 0, stream>>>(sa_wqk, wqkb, 512, 128, 128);
  cast2d_k<<<256,  256, 0, stream>>>(sa_wv,  wvb,  512, 128, 128);
  cast2d_k<<<256,  256, 0, stream>>>(sa_wt,  wtb,  512, 128, 128);
  cast2d_k<<<2048, 256, 0, stream>>>(wf,     wfb,  1024, 512, 512);
  cast2d_k<<<2048, 256, 0, stream>>>(ws1,    ws1b, 512, 1024, 3072);
  cast2d_k<<<100,  256, 0, stream>>>(ws2,    ws2b, 50, 512, 512);

  const long sAct = 262144, sFeat = 1048576, sFus = 2097152;
  for (int b0 = 0; b0 < B_; b0 += Gb) {
    int g = Gb;
    conv1_k<<<dim3(N_, g), 128, 0, stream>>>(x + (long)b0 * 3 * N_, w1,
                                             bn1_g, bn1_b, bn1_m, bn1_v, h0);
    // conv2 + bn2 + relu -> h1 (fp32 token)
    gemm_tok<<<dim3(16, 1, g), 256, 0, stream>>>(
        w2b, h0, sAct, 128, nullptr, 0, 0, nullptr, nullptr, 0,
        bn2_g, bn2_b, bn2_m, bn2_v, nullptr, 0, 0,
        h1, sAct, 128, 1, nullptr, 0, 0, 0, 128, 128, 1);

    for (int i = 0; i < 4; ++i) {
      const float* li = (i == 0) ? h1 : feats + (size_t)(i - 1) * 128;
      int ldLi = (i == 0) ? 128 : 512;
      long sLi = (i == 0) ? sAct : sFeat;
      // xk (bf16 token)
      gemm_tok<<<dim3(16, 1, g), 256, 0, stream>>>(
          wqkb + (size_t)i * 128 * 128, li, sLi, ldLi, nullptr, 0, 0,
          nullptr, nullptr, 0, nullptr, nullptr, nullptr, nullptr, nullptr, 0, 0,
          nullptr, 0, 0, 0, xkb, sAct, 128, 1, 128, 128, 0);
      // xv (bf16 channel)
      gemm_tok<<<dim3(16, 1, g), 256, 0, stream>>>(
          wvb + (size_t)i * 128 * 128, li, sLi, ldLi, nullptr, 0, 0,
          sa_bv + i * 128, nullptr, 0, nullptr, nullptr, nullptr, nullptr, nullptr, 0, 0,
          nullptr, 0, 0, 0, xvb, sAct, 2048, 2, 128, 128, 0);
      // attention stats + fused PV
      gram_stats<<<dim3(32, g), 256, 0, stream>>>(xkb, sAct, mxB, rsB, csB, 0);
      gram_stats<<<dim3(32, g), 256, 0, stream>>>(xkb, sAct, mxB, rsB, csB, 1);
      pv_k<<<dim3(32, g), 256, 0, stream>>>(xkb, sAct, xvb, sAct, mxB, rsB, csB, xr, sAct);
      // feats_i = li + relu(bn(wt @ (li - xr) + bt))
      gemm_tok<<<dim3(16, 1, g), 256, 0, stream>>>(
          wtb + (size_t)i * 128 * 128, li, sLi, ldLi, xr, sAct, 128,
          sa_bt + i * 128, nullptr, 0,
          sa_g + i * 128, sa_b + i * 128, sa_m + i * 128, sa_v + i * 128,
          li, sLi, ldLi,
          feats + (size_t)i * 128, sFeat, 512, 1, nullptr, 0, 0, 0, 128, 128, 1);
    }

    // fused = leaky(bn(wf @ feats))
    gemm_tok<<<dim3(16, 8, g), 256, 0, stream>>>(
        wfb, feats, sFeat, 512, nullptr, 0, 0, nullptr, nullptr, 0,
        bnf_g, bnf_b, bnf_m, bnf_v, nullptr, 0, 0,
        fused, sFus, 1024, 1, nullptr, 0, 0, 0, 512, 1024, 2);
    poolpart_k<<<dim3(4, 16, g), 256, 0, stream>>>(fused, sFus, pmax, psum);
    poolred_k<<<dim3(4, g), 256, 0, stream>>>(pmax, psum, xmaxB, xavgB);
    poolterm_k<<<dim3(512, g), 256, 0, stream>>>(ws1, xmaxB, xavgB, ptB);
    // hs1 = relu(bn(ws1 @ [fused;pool] + bs1))
    gemm_tok<<<dim3(16, 4, g), 256, 0, stream>>>(
        ws1b, fused, sFus, 1024, nullptr, 0, 0, bs1, ptB, 512,
        bns1_g, bns1_b, bns1_m, bns1_v, nullptr, 0, 0,
        hs1, sFeat, 512, 1, nullptr, 0, 0, 0, 1024, 512, 1);
    // out = relu(bn(ws2 @ hs1 + bs2))  (fp32 channel-major)
    gemm_tok<<<dim3(16, 1, g), 256, 0, stream>>>(
        ws2b, hs1, sFeat, 512, nullptr, 0, 0, bs2, nullptr, 0,
        bns2_g, bns2_b, bns2_m, bns2_v, nullptr, 0, 0,
        out + (long)b0 * OUT_ * N_, (long)OUT_ * N_, 2048, 2,
        nullptr, 0, 0, 0, 512, 50, 1);
  }
}

// Round 4
// 1076.026 us; speedup vs baseline: 5.3084x; 1.2758x over previous
//
#include <hip/hip_runtime.h>
#include <cstdint>
#include <cstddef>

#define B_   16
#define N_   2048
#define D_   128
#define F_   1024
#define H1_  512
#define OUT_ 50

static constexpr float BN_EPS = 1e-5f;

typedef __attribute__((ext_vector_type(8))) short short8;
typedef __attribute__((ext_vector_type(4))) float f32x4;

__device__ inline unsigned short f2bf(float f) {
  union { float f; unsigned u; } v; v.f = f;
  unsigned r = v.u + 0x7fff + ((v.u >> 16) & 1);
  return (unsigned short)(r >> 16);
}

// async global->LDS, 16B per lane; LDS dest = wave-uniform base + lane*16
__device__ inline void dma16(const unsigned short* g, unsigned short* l) {
  __builtin_amdgcn_global_load_lds(
      (const __attribute__((address_space(1))) unsigned int*)g,
      (__attribute__((address_space(3))) unsigned int*)l, 16, 0, 0);
}

// ---------------------------------------------------------------------------
// cast fp32 [R][ldSrc] (first C cols) -> bf16 [R][C] row-major
// ---------------------------------------------------------------------------
__global__ void cast2d_k(const float* __restrict__ src, unsigned short* __restrict__ dst,
                         int R, int C, int ldSrc) {
  long i = (long)blockIdx.x * 256 + threadIdx.x;
  if (i >= (long)R * C) return;
  int r = (int)(i / C), c = (int)(i % C);
  dst[i] = f2bf(src[(long)r * ldSrc + c]);
}

// ---------------------------------------------------------------------------
// conv1 (3->128) + bn + relu -> bf16 token-major. grid (N, g), block 128
// ---------------------------------------------------------------------------
__global__ void conv1_k(const float* __restrict__ x, const float* __restrict__ w1,
                        const float* __restrict__ g, const float* __restrict__ bb,
                        const float* __restrict__ m, const float* __restrict__ v,
                        unsigned short* __restrict__ h0b) {
  int o = threadIdx.x, n = blockIdx.x, b = blockIdx.y;
  const float* xb = x + (long)b * 3 * N_;
  float val = w1[o * 3 + 0] * xb[n] + w1[o * 3 + 1] * xb[N_ + n] + w1[o * 3 + 2] * xb[2 * N_ + n];
  float sc = g[o] * rsqrtf(v[o] + BN_EPS);
  val = val * sc + (bb[o] - m[o] * sc);
  h0b[((long)b * N_ + n) * D_ + o] = f2bf(fmaxf(val, 0.f));
}

// ---------------------------------------------------------------------------
// bf16 MFMA GEMM, m97-style staging. out[n][o] = epi( sum_k A[n][k]*W[o][k] )
// A bf16 token-major (ldA), W bf16 [O][K] (ldW), both DMA-staged with XOR
// swizzle (lds seg = gseg ^ (row&7)). Tile 128x128, BK=64, block 256.
// flags: 1 outF token fp32 | 2 outF channel fp32 | 4 outH token bf16 |
//        16 add res (fp32 token) after act | 32 pool partials | 64 kv-split
// ---------------------------------------------------------------------------
__global__ __launch_bounds__(256)
void gemm_bf(const unsigned short* __restrict__ Wb, int ldW,
             const unsigned short* __restrict__ A, long sA, int ldA,
             const float* __restrict__ bias, const float* __restrict__ bias2,
             const float* __restrict__ perBO, int ldPBO,
             const float* __restrict__ bng, const float* __restrict__ bnb,
             const float* __restrict__ bnm, const float* __restrict__ bnv,
             const float* __restrict__ res, long sRes, int ldRes,
             float* __restrict__ outF, long sOutF, int ldOutF,
             unsigned short* __restrict__ outH, long sOutH, int ldOutH,
             unsigned short* __restrict__ outH2, long sOutH2, int ldOutH2,
             float* __restrict__ pmax, float* __restrict__ psum,
             int K, int O, int act, int flags) {
  __shared__ unsigned short lA[128 * 64];
  __shared__ unsigned short lB[128 * 64];
  __shared__ float lpm[4][64], lps[4][64];
  int tid = threadIdx.x;
  int n0 = blockIdx.x * 128, o0 = blockIdx.y * 128, b = blockIdx.z;
  int wave = tid >> 6, lane = tid & 63;
  int wr = wave >> 1, wc = wave & 1;
  int quad = lane >> 4, l15 = lane & 15;
  int rowL = lane >> 3;                 // 0..7 within 8-row chunk
  int kseg = (lane & 7) ^ rowL;         // swizzled 16B segment to FETCH
  const unsigned short* Ab = A + (long)b * sA + (long)n0 * ldA;
  const unsigned short* Wp = Wb + (long)o0 * ldW;

  f32x4 acc[4][4];
  #pragma unroll
  for (int i = 0; i < 4; ++i)
    #pragma unroll
    for (int j = 0; j < 4; ++j) acc[i][j] = (f32x4){0.f, 0.f, 0.f, 0.f};

  for (int kc = 0; kc < K; kc += 64) {
    #pragma unroll
    for (int t = 0; t < 4; ++t) {
      int chunk = t * 4 + wave;          // 0..15, wave-uniform
      int row = chunk * 8 + rowL;        // 0..127
      dma16(Ab + (long)row * ldA + kc + kseg * 8, &lA[chunk * 512]);
      dma16(Wp + (long)row * ldW + kc + kseg * 8, &lB[chunk * 512]);
    }
    __syncthreads();
    #pragma unroll
    for (int kk = 0; kk < 2; ++kk) {
      short8 af[4], bf[4];
      #pragma unroll
      for (int mt = 0; mt < 4; ++mt) {
        int r = wr * 64 + mt * 16 + l15;
        af[mt] = *(const short8*)&lA[r * 64 + (((kk * 4 + quad) ^ (l15 & 7)) * 8)];
      }
      #pragma unroll
      for (int ot = 0; ot < 4; ++ot) {
        int r = wc * 64 + ot * 16 + l15;
        bf[ot] = *(const short8*)&lB[r * 64 + (((kk * 4 + quad) ^ (l15 & 7)) * 8)];
      }
      #pragma unroll
      for (int mt = 0; mt < 4; ++mt)
        #pragma unroll
        for (int ot = 0; ot < 4; ++ot)
          acc[mt][ot] = __builtin_amdgcn_mfma_f32_16x16x32_bf16(af[mt], bf[ot], acc[mt][ot], 0, 0, 0);
    }
    __syncthreads();
  }

  bool isV = (flags & 64) && (o0 >= 128);
  float colMax[4], colSum[4];
  #pragma unroll
  for (int ot = 0; ot < 4; ++ot) { colMax[ot] = -1e30f; colSum[ot] = 0.f; }

  #pragma unroll
  for (int ot = 0; ot < 4; ++ot) {
    int o = o0 + wc * 64 + ot * 16 + l15;
    bool valid = (o < O);
    float bi = 0.f, sc = 1.f, sh = 0.f;
    if (valid) {
      if (flags & 64) { if (isV) bi = bias2[o - 128]; }
      else if (bias) bi = bias[o];
      if (perBO) bi += perBO[(long)b * ldPBO + o];
      if (bng) { sc = bng[o] * rsqrtf(bnv[o] + BN_EPS); sh = bnb[o] - bnm[o] * sc; }
    }
    #pragma unroll
    for (int mt = 0; mt < 4; ++mt) {
      int nb = n0 + wr * 64 + mt * 16 + quad * 4;
      float vals[4];
      #pragma unroll
      for (int r = 0; r < 4; ++r) {
        float val = acc[mt][ot][r] + bi;
        val = val * sc + sh;
        if (act == 1)      val = fmaxf(val, 0.f);
        else if (act == 2) val = (val >= 0.f) ? val : 0.2f * val;
        if (flags & 16) val += res[(long)b * sRes + (long)(nb + r) * ldRes + o];
        vals[r] = val;
      }
      if (valid) {
        if (flags & 64) {
          if (isV) {
            unsigned short t[4];
            #pragma unroll
            for (int r = 0; r < 4; ++r) t[r] = f2bf(vals[r]);
            *(uint2*)&outH2[(long)b * sOutH2 + (long)(o - 128) * ldOutH2 + nb] = *(uint2*)&t[0];
          } else {
            #pragma unroll
            for (int r = 0; r < 4; ++r)
              outH[(long)b * sOutH + (long)(nb + r) * ldOutH + o] = f2bf(vals[r]);
          }
        } else {
          if (flags & 1) {
            #pragma unroll
            for (int r = 0; r < 4; ++r)
              outF[(long)b * sOutF + (long)(nb + r) * ldOutF + o] = vals[r];
          }
          if (flags & 2) {
            *(float4*)&outF[(long)b * sOutF + (long)o * ldOutF + nb] = *(float4*)vals;
          }
          if (flags & 4) {
            #pragma unroll
            for (int r = 0; r < 4; ++r)
              outH[(long)b * sOutH + (long)(nb + r) * ldOutH + o] = f2bf(vals[r]);
          }
        }
      }
      if (flags & 32) {
        #pragma unroll
        for (int r = 0; r < 4; ++r) { colMax[ot] = fmaxf(colMax[ot], vals[r]); colSum[ot] += vals[r]; }
      }
    }
  }
  if (flags & 32) {
    #pragma unroll
    for (int ot = 0; ot < 4; ++ot) {
      float m = colMax[ot], s = colSum[ot];
      m = fmaxf(m, __shfl_xor(m, 16)); s += __shfl_xor(s, 16);
      m = fmaxf(m, __shfl_xor(m, 32)); s += __shfl_xor(s, 32);
      if (quad == 0) { lpm[wave][ot * 16 + l15] = m; lps[wave][ot * 16 + l15] = s; }
    }
    __syncthreads();
    if (tid < 128) {
      int wcx = tid >> 6, ol = tid & 63;
      float m = fmaxf(lpm[wcx][ol], lpm[wcx + 2][ol]);
      float s = lps[wcx][ol] + lps[wcx + 2][ol];
      int o = o0 + wcx * 64 + ol;
      pmax[((long)b * 16 + blockIdx.x) * 1024 + o] = m;
      psum[((long)b * 16 + blockIdx.x) * 1024 + o] = s;
    }
  }
}

// ---------------------------------------------------------------------------
// Gram row-stats (softmax mx/rs only). E[n][m] = xk[n]�xk[m], K=128.
// xk bf16 token [2048][128]. grid (32, g), block 256.
// ---------------------------------------------------------------------------
__global__ __launch_bounds__(256)
void gram_stats(const unsigned short* __restrict__ xk, long sXk,
                float* __restrict__ mx, float* __restrict__ rs) {
  __shared__ unsigned short lK[64 * 136];
  int tid = threadIdx.x, wave = tid >> 6, lane = tid & 63;
  int quad = lane >> 4, l15 = lane & 15;
  int n0 = blockIdx.x * 64, b = blockIdx.y;
  const unsigned short* Kp = xk + (long)b * sXk;
  short8 afr[4];
  {
    const unsigned short* arow = Kp + (long)(n0 + wave * 16 + l15) * 128;
    #pragma unroll
    for (int kf = 0; kf < 4; ++kf) afr[kf] = *(const short8*)(arow + kf * 32 + quad * 8);
  }
  float runm[4], runs[4];
  #pragma unroll
  for (int r = 0; r < 4; ++r) { runm[r] = -1e30f; runs[r] = 0.f; }

  for (int m0 = 0; m0 < 2048; m0 += 64) {
    __syncthreads();
    {
      int r = tid >> 2, seg = tid & 3;
      const unsigned short* src = Kp + (long)(m0 + r) * 128 + seg * 32;
      #pragma unroll
      for (int q = 0; q < 4; ++q)
        *(uint4*)&lK[r * 136 + seg * 32 + q * 8] = *(const uint4*)(src + q * 8);
    }
    __syncthreads();
    #pragma unroll
    for (int mf = 0; mf < 4; ++mf) {
      f32x4 s = (f32x4){0.f, 0.f, 0.f, 0.f};
      #pragma unroll
      for (int kf = 0; kf < 4; ++kf) {
        short8 bfr = *(const short8*)&lK[(mf * 16 + l15) * 136 + kf * 32 + quad * 8];
        s = __builtin_amdgcn_mfma_f32_16x16x32_bf16(afr[kf], bfr, s, 0, 0, 0);
      }
      #pragma unroll
      for (int r = 0; r < 4; ++r) {
        float e = s[r];
        float mn = fmaxf(runm[r], e);
        runs[r] = runs[r] * __expf(runm[r] - mn) + __expf(e - mn);
        runm[r] = mn;
      }
    }
  }
  #pragma unroll
  for (int r = 0; r < 4; ++r) {
    float m = runm[r], s = runs[r];
    #pragma unroll
    for (int off = 1; off < 16; off <<= 1) {
      float mo = __shfl_xor(m, off), so = __shfl_xor(s, off);
      float mn = fmaxf(m, mo);
      s = s * __expf(m - mn) + so * __expf(mo - mn);
      m = mn;
    }
    if (l15 == 0) {
      int n = n0 + wave * 16 + quad * 4 + r;
      mx[(long)b * 2048 + n] = m; rs[(long)b * 2048 + n] = s;
    }
  }
}

// ---------------------------------------------------------------------------
// Fused PV + colsum + output transform:
//   p[m][n] = exp(E[m][n]-mx[n])/rs[n]  (= P[n][m] by symmetry)
//   cs[m]   = sum_n p[m][n]             (computed in-block)
//   xrb[m][d] = bf16( li[m][d] - (sum_n p[m][n]*xv[d][n]) / (1e-9+cs[m]) )
// grid (32, g), block 256.
// ---------------------------------------------------------------------------
__global__ __launch_bounds__(256)
void pv_k(const unsigned short* __restrict__ xk, long sXk,
          const unsigned short* __restrict__ xv, long sXv,
          const float* __restrict__ mx, const float* __restrict__ rs,
          const float* __restrict__ li, long sLi, int ldLi,
          unsigned short* __restrict__ xrb, long sXr) {
  __shared__ unsigned short lK[64 * 136];
  __shared__ unsigned short lV[128 * 72];
  __shared__ unsigned short lP[4][16 * 72];
  __shared__ float lmx[2048], lrs[2048];
  int tid = threadIdx.x, wave = tid >> 6, lane = tid & 63;
  int quad = lane >> 4, l15 = lane & 15;
  int m0 = blockIdx.x * 64, b = blockIdx.y;
  const unsigned short* Kp = xk + (long)b * sXk;
  const unsigned short* Vp = xv + (long)b * sXv;
  for (int i = tid; i < 2048; i += 256) { lmx[i] = mx[(long)b * 2048 + i]; lrs[i] = rs[(long)b * 2048 + i]; }
  short8 akr[4];
  {
    const unsigned short* arow = Kp + (long)(m0 + wave * 16 + l15) * 128;
    #pragma unroll
    for (int kf = 0; kf < 4; ++kf) akr[kf] = *(const short8*)(arow + kf * 32 + quad * 8);
  }
  f32x4 acc[8];
  #pragma unroll
  for (int dt = 0; dt < 8; ++dt) acc[dt] = (f32x4){0.f, 0.f, 0.f, 0.f};
  float runc[4] = {0.f, 0.f, 0.f, 0.f};

  for (int n0 = 0; n0 < 2048; n0 += 64) {
    __syncthreads();
    {
      int r = tid >> 2, seg = tid & 3;
      const unsigned short* src = Kp + (long)(n0 + r) * 128 + seg * 32;
      #pragma unroll
      for (int q = 0; q < 4; ++q)
        *(uint4*)&lK[r * 136 + seg * 32 + q * 8] = *(const uint4*)(src + q * 8);
    }
    {
      int d = tid >> 1, half = (tid & 1) * 32;
      const unsigned short* src = Vp + (long)d * 2048 + n0 + half;
      #pragma unroll
      for (int q = 0; q < 4; ++q)
        *(uint4*)&lV[d * 72 + half + q * 8] = *(const uint4*)(src + q * 8);
    }
    __syncthreads();
    #pragma unroll
    for (int nf = 0; nf < 4; ++nf) {
      f32x4 s = (f32x4){0.f, 0.f, 0.f, 0.f};
      #pragma unroll
      for (int kf = 0; kf < 4; ++kf) {
        short8 bfr = *(const short8*)&lK[(nf * 16 + l15) * 136 + kf * 32 + quad * 8];
        s = __builtin_amdgcn_mfma_f32_16x16x32_bf16(akr[kf], bfr, s, 0, 0, 0);
      }
      int col = n0 + nf * 16 + l15;
      float mc = lmx[col], rcInv = 1.f / lrs[col];
      #pragma unroll
      for (int r = 0; r < 4; ++r) {
        float p = __expf(s[r] - mc) * rcInv;
        runc[r] += p;
        lP[wave][(quad * 4 + r) * 72 + nf * 16 + l15] = f2bf(p);
      }
    }
    __syncthreads();
    #pragma unroll
    for (int kc = 0; kc < 2; ++kc) {
      short8 pa = *(const short8*)&lP[wave][l15 * 72 + kc * 32 + quad * 8];
      #pragma unroll
      for (int dt = 0; dt < 8; ++dt) {
        short8 vb = *(const short8*)&lV[(dt * 16 + l15) * 72 + kc * 32 + quad * 8];
        acc[dt] = __builtin_amdgcn_mfma_f32_16x16x32_bf16(pa, vb, acc[dt], 0, 0, 0);
      }
    }
  }
  float inv[4];
  #pragma unroll
  for (int r = 0; r < 4; ++r) {
    float s = runc[r];
    #pragma unroll
    for (int off = 1; off < 16; off <<= 1) s += __shfl_xor(s, off);
    inv[r] = 1.f / (1e-9f + s);
  }
  #pragma unroll
  for (int dt = 0; dt < 8; ++dt) {
    int d = dt * 16 + l15;
    #pragma unroll
    for (int r = 0; r < 4; ++r) {
      int m = m0 + wave * 16 + quad * 4 + r;
      float lv = li[(long)b * sLi + (long)m * ldLi + d];
      xrb[(long)b * sXr + (long)m * 128 + d] = f2bf(lv - acc[dt][r] * inv[r]);
    }
  }
}

// ---------------------------------------------------------------------------
__global__ void poolred_k(const float* __restrict__ pmax, const float* __restrict__ psum,
                          float* __restrict__ xmax, float* __restrict__ xavg) {
  int f = blockIdx.x * 256 + threadIdx.x, b = blockIdx.y;
  float mx = -1e30f, s = 0.f;
  #pragma unroll
  for (int t = 0; t < 16; ++t) {
    mx = fmaxf(mx, pmax[((long)b * 16 + t) * 1024 + f]);
    s += psum[((long)b * 16 + t) * 1024 + f];
  }
  xmax[(long)b * 1024 + f] = mx;
  xavg[(long)b * 1024 + f] = s * (1.f / 2048.f);
}

__global__ __launch_bounds__(256)
void poolterm_k(const float* __restrict__ ws1, const float* __restrict__ xmax,
                const float* __restrict__ xavg, float* __restrict__ pt) {
  int o = blockIdx.x, b = blockIdx.y, tid = threadIdx.x;
  const float* w = ws1 + (long)o * 3072;
  float s = 0.f;
  #pragma unroll
  for (int it = 0; it < 4; ++it) {
    int c = tid + it * 256;
    s += w[1024 + c] * xmax[(long)b * 1024 + c] + w[2048 + c] * xavg[(long)b * 1024 + c];
  }
  #pragma unroll
  for (int off = 32; off; off >>= 1) s += __shfl_xor(s, off);
  __shared__ float rsm[4];
  if ((tid & 63) == 0) rsm[tid >> 6] = s;
  __syncthreads();
  if (tid == 0) pt[(long)b * H1_ + o] = rsm[0] + rsm[1] + rsm[2] + rsm[3];
}

// ---------------------------------------------------------------------------
extern "C" void kernel_launch(void* const* d_in, const int* in_sizes, int n_in,
                              void* d_out, int out_size, void* d_ws, size_t ws_size,
                              hipStream_t stream) {
  const float* x      = (const float*)d_in[0];
  const float* w1     = (const float*)d_in[1];
  const float* w2     = (const float*)d_in[2];
  const float* bn1_g  = (const float*)d_in[3];
  const float* bn1_b  = (const float*)d_in[4];
  const float* bn1_m  = (const float*)d_in[5];
  const float* bn1_v  = (const float*)d_in[6];
  const float* bn2_g  = (const float*)d_in[7];
  const float* bn2_b  = (const float*)d_in[8];
  const float* bn2_m  = (const float*)d_in[9];
  const float* bn2_v  = (const float*)d_in[10];
  const float* sa_wqk = (const float*)d_in[11];
  const float* sa_wv  = (const float*)d_in[12];
  const float* sa_bv  = (const float*)d_in[13];
  const float* sa_wt  = (const float*)d_in[14];
  const float* sa_bt  = (const float*)d_in[15];
  const float* sa_g   = (const float*)d_in[16];
  const float* sa_b   = (const float*)d_in[17];
  const float* sa_m   = (const float*)d_in[18];
  const float* sa_v   = (const float*)d_in[19];
  const float* wf     = (const float*)d_in[20];
  const float* bnf_g  = (const float*)d_in[21];
  const float* bnf_b  = (const float*)d_in[22];
  const float* bnf_m  = (const float*)d_in[23];
  const float* bnf_v  = (const float*)d_in[24];
  const float* ws1    = (const float*)d_in[25];
  const float* bs1    = (const float*)d_in[26];
  const float* bns1_g = (const float*)d_in[27];
  const float* bns1_b = (const float*)d_in[28];
  const float* bns1_m = (const float*)d_in[29];
  const float* bns1_v = (const float*)d_in[30];
  const float* ws2    = (const float*)d_in[31];
  const float* bs2    = (const float*)d_in[32];
  const float* bns2_g = (const float*)d_in[33];
  const float* bns2_b = (const float*)d_in[34];
  const float* bns2_m = (const float*)d_in[35];
  const float* bns2_v = (const float*)d_in[36];
  float* out = (float*)d_out;

  float* ws = (float*)d_ws;
  size_t off = 0;
  auto alloc  = [&](size_t n) { float* p = ws + off; off += (n + 63) & ~(size_t)63; return p; };
  auto allocH = [&](size_t n) { return (unsigned short*)alloc((n + 1) / 2); };

  // ---- fixed: bf16 weights (+padding for DMA tiles) + reductions ----
  unsigned short* w2b  = allocH(128 * 128);
  unsigned short* wqvb = allocH(4 * 256 * 128);          // [wqk_i ; wv_i]
  unsigned short* wtb  = allocH(4 * 128 * 128);
  unsigned short* wfb  = allocH((size_t)F_ * 512);
  unsigned short* ws1b = allocH((size_t)H1_ * 1024);
  unsigned short* ws2b = allocH((size_t)128 * 512);      // padded to 128 rows
  float* mxB  = alloc((size_t)16 * 2048);
  float* rsB  = alloc((size_t)16 * 2048);
  float* pmax = alloc((size_t)16 * 16 * 1024);
  float* psum = alloc((size_t)16 * 16 * 1024);
  float* xmaxB = alloc((size_t)16 * 1024);
  float* xavgB = alloc((size_t)16 * 1024);
  float* ptB   = alloc((size_t)16 * 512);
  size_t fixedOff = off;

  // ---- per-batch floats: h1 + feats fp32, bf16 copies (as half-floats) ----
  const size_t perB = 262144 /*h1*/ + 1048576 /*feats*/ +
                      131072 /*h1b*/ + 524288 /*featsb|hs1b*/ + 1048576 /*fusedb*/ +
                      131072 /*xkb*/ + 131072 /*xvb*/ + 131072 /*xrb|h0b*/;
  size_t wsFloats = ws_size / 4;
  int Gb = 1;
  for (int c : {16, 8, 4, 2, 1}) {
    if (fixedOff + (size_t)c * perB + 4096 <= wsFloats) { Gb = c; break; }
  }

  float* h1    = alloc((size_t)Gb * 262144);
  float* feats = alloc((size_t)Gb * 1048576);
  unsigned short* h1b    = allocH((size_t)Gb * 262144);
  unsigned short* featsb = allocH((size_t)Gb * 1048576);   // hs1b aliases
  unsigned short* fusedb = allocH((size_t)Gb * 2097152);
  unsigned short* xkb    = allocH((size_t)Gb * 262144);
  unsigned short* xvb    = allocH((size_t)Gb * 262144);
  unsigned short* xrb    = allocH((size_t)Gb * 262144);    // h0b aliases
  unsigned short* h0b  = xrb;
  unsigned short* hs1b = featsb;

  // ---- one-time weight casts ----
  cast2d_k<<<64, 256, 0, stream>>>(w2, w2b, 128, 128, 128);
  for (int i = 0; i < 4; ++i) {
    cast2d_k<<<64, 256, 0, stream>>>(sa_wqk + (size_t)i * 16384, wqvb + (size_t)i * 32768, 128, 128, 128);
    cast2d_k<<<64, 256, 0, stream>>>(sa_wv  + (size_t)i * 16384, wqvb + (size_t)i * 32768 + 16384, 128, 128, 128);
    cast2d_k<<<64, 256, 0, stream>>>(sa_wt  + (size_t)i * 16384, wtb  + (size_t)i * 16384, 128, 128, 128);
  }
  cast2d_k<<<2048, 256, 0, stream>>>(wf,  wfb,  1024, 512, 512);
  cast2d_k<<<2048, 256, 0, stream>>>(ws1, ws1b, 512, 1024, 3072);
  cast2d_k<<<100,  256, 0, stream>>>(ws2, ws2b, 50, 512, 512);

  const long sAct = 262144, sFeat = 1048576, sFus = 2097152;
  for (int b0 = 0; b0 < B_; b0 += Gb) {
    int g = Gb;
    conv1_k<<<dim3(N_, g), 128, 0, stream>>>(x + (long)b0 * 3 * N_, w1,
                                             bn1_g, bn1_b, bn1_m, bn1_v, h0b);
    // conv2 + bn2 + relu -> h1 fp32 + h1b bf16 (token)
    gemm_bf<<<dim3(16, 1, g), 256, 0, stream>>>(
        w2b, 128, h0b, sAct, 128, nullptr, nullptr, nullptr, 0,
        bn2_g, bn2_b, bn2_m, bn2_v, nullptr, 0, 0,
        h1, sAct, 128, h1b, sAct, 128, nullptr, 0, 0,
        nullptr, nullptr, 128, 128, 1, 1 | 4);

    for (int i = 0; i < 4; ++i) {
      const unsigned short* lib = (i == 0) ? h1b : featsb + (size_t)(i - 1) * 128;
      const float* liF = (i == 0) ? h1 : feats + (size_t)(i - 1) * 128;
      int ldLi = (i == 0) ? 128 : 512;
      long sLi = (i == 0) ? sAct : sFeat;
      // xk (token bf16) + xv (channel bf16, +bv) in one dispatch
      gemm_bf<<<dim3(16, 2, g), 256, 0, stream>>>(
          wqvb + (size_t)i * 32768, 128, lib, sLi, ldLi,
          nullptr, sa_bv + i * 128, nullptr, 0,
          nullptr, nullptr, nullptr, nullptr, nullptr, 0, 0,
          nullptr, 0, 0, xkb, sAct, 128, xvb, sAct, 2048,
          nullptr, nullptr, 128, 256, 0, 64);
      gram_stats<<<dim3(32, g), 256, 0, stream>>>(xkb, sAct, mxB, rsB);
      pv_k<<<dim3(32, g), 256, 0, stream>>>(xkb, sAct, xvb, sAct, mxB, rsB,
                                            liF, sLi, ldLi, xrb, sAct);
      // feats_i = li + relu(bn(wt @ (li - xr) + bt));  A = xrb = bf16(li-xr)
      gemm_bf<<<dim3(16, 1, g), 256, 0, stream>>>(
          wtb + (size_t)i * 16384, 128, xrb, sAct, 128,
          sa_bt + i * 128, nullptr, nullptr, 0,
          sa_g + i * 128, sa_b + i * 128, sa_m + i * 128, sa_v + i * 128,
          liF, sLi, ldLi,
          feats + (size_t)i * 128, sFeat, 512,
          featsb + (size_t)i * 128, sFeat, 512, nullptr, 0, 0,
          nullptr, nullptr, 128, 128, 1, 1 | 4 | 16);
    }

    // fused = leaky(bn(wf @ feats)) -> bf16 + pool partials
    gemm_bf<<<dim3(16, 8, g), 256, 0, stream>>>(
        wfb, 512, featsb, sFeat, 512, nullptr, nullptr, nullptr, 0,
        bnf_g, bnf_b, bnf_m, bnf_v, nullptr, 0, 0,
        nullptr, 0, 0, fusedb, sFus, 1024, nullptr, 0, 0,
        pmax, psum, 512, 1024, 2, 4 | 32);
    poolred_k<<<dim3(4, g), 256, 0, stream>>>(pmax, psum, xmaxB, xavgB);
    poolterm_k<<<dim3(512, g), 256, 0, stream>>>(ws1, xmaxB, xavgB, ptB);
    // hs1 = relu(bn(ws1 @ [fused;pool] + bs1)) -> bf16
    gemm_bf<<<dim3(16, 4, g), 256, 0, stream>>>(
        ws1b, 1024, fusedb, sFus, 1024, bs1, nullptr, ptB, 512,
        bns1_g, bns1_b, bns1_m, bns1_v, nullptr, 0, 0,
        nullptr, 0, 0, hs1b, sFeat, 512, nullptr, 0, 0,
        nullptr, nullptr, 1024, 512, 1, 4);
    // out = relu(bn(ws2 @ hs1 + bs2)) -> fp32 channel-major
    gemm_bf<<<dim3(16, 1, g), 256, 0, stream>>>(
        ws2b, 512, hs1b, sFeat, 512, bs2, nullptr, nullptr, 0,
        bns2_g, bns2_b, bns2_m, bns2_v, nullptr, 0, 0,
        out + (long)b0 * OUT_ * N_, (long)OUT_ * N_, 2048,
        nullptr, 0, 0, nullptr, 0, 0,
        nullptr, nullptr, 512, 50, 1, 2);
  }
}